// Round 6
// baseline (81.149 us; speedup 1.0000x reference)
//
#include <hip/hip_runtime.h>
#include <stdint.h>
#include <math.h>

typedef __bf16 bf16;
typedef __bf16 bf16x8 __attribute__((ext_vector_type(8)));
typedef __bf16 bf16x4 __attribute__((ext_vector_type(4)));
typedef float f32x4 __attribute__((ext_vector_type(4)));

static constexpr int BATCH = 16384;
static constexpr int D_IN  = 1024;
static constexpr int UNITS = 512;
static constexpr int D_OUT = 512;

__device__ __forceinline__ void gll16(const void* g, void* l) {
    __builtin_amdgcn_global_load_lds(
        (const __attribute__((address_space(1))) void*)g,
        (__attribute__((address_space(3))) void*)l,
        16, 0, 0);
}

// counted vmcnt wait (lgkm/exp = no-wait); N must be < 16
template<int N>
__device__ __forceinline__ void waitvm() {
    static_assert(N < 16, "vmcnt imm");
    __builtin_amdgcn_s_waitcnt(0x0F70 | N);
    asm volatile("" ::: "memory");
}
__device__ __forceinline__ void barrier_raw() {
    asm volatile("" ::: "memory");
    __builtin_amdgcn_s_barrier();
    asm volatile("" ::: "memory");
}

// ---------------- fused weight prep: one launch ----------------
__global__ __launch_bounds__(256)
void k_prep(const float* __restrict__ w_in, const float* __restrict__ sens_w,
            const float* __restrict__ ro_w,
            bf16* __restrict__ w_in_bf, bf16* __restrict__ sensT, bf16* __restrict__ ro_bf)
{
    __shared__ float tile[32][33];
    const int b = blockIdx.x;
    const int t = threadIdx.x;
    if (b < 512) {
        int i = b * 256 + t;
        f32x4 v = ((const f32x4*)w_in)[i];
        bf16x4 o = { (bf16)v.x, (bf16)v.y, (bf16)v.z, (bf16)v.w };
        ((bf16x4*)w_in_bf)[i] = o;
    } else if (b < 768) {
        int bb = b - 512;
        int bx = bb & 15, by = bb >> 4;
        int tx = t & 31, ty = t >> 5;
        #pragma unroll
        for (int j = ty; j < 32; j += 8)
            tile[j][tx] = sens_w[(size_t)(by * 32 + j) * UNITS + bx * 32 + tx];
        __syncthreads();
        #pragma unroll
        for (int j = ty; j < 32; j += 8)
            sensT[(size_t)(bx * 32 + j) * UNITS + by * 32 + tx] = (bf16)tile[tx][j];
    } else {
        int i = (b - 768) * 256 + t;
        f32x4 v = ((const f32x4*)ro_w)[i];
        bf16x4 o = { (bf16)v.x, (bf16)v.y, (bf16)v.z, (bf16)v.w };
        ((bf16x4*)ro_bf)[i] = o;
    }
}

// ---------------- fused GEMM: 4 waves @ 64x64, counted-vmcnt LDS ring ----------------
// C[M,N] = epilogue( A[M,K] @ Bw[N,K]^T + bias ), 128x128 block tile, 256 thr.
// 4 waves @ 64x64 halves LDS fragment-read traffic vs 8 waves @ 32x64
// (per-wave frag bytes = (Wm+Wn)*BK; the kernel family is LDS-BW-bound).
// XOR bank-swizzles (rule 21, involution on stage-source AND read):
//   bf16 tiles: slot16 ^= (row>>1)&3  -> 2-way (free)
//   fp32 A:     slot16 ^= row&7       -> 2-way (free)
// DEPTH-deep ring, raw s_barrier + counted vmcnt (never 0 in steady state).
// EPI 1: out_bf16 = tanh(.)  EPI 2: sigmoid + ODE decay  EPI 3: identity
template<int K, int EPI, bool AF32, int DEPTH>
__global__ __launch_bounds__(256, 2)
void k_gemm(const float* __restrict__ Af, const bf16* __restrict__ Ab,
            const bf16* __restrict__ Bw,
            const float* __restrict__ bias,
            const float* __restrict__ tau,
            const float* __restrict__ states,
            float* __restrict__ outF, bf16* __restrict__ outB,
            int M, int N)
{
    constexpr int NSTEP = K / 32;
    constexpr int L = AF32 ? 6 : 4;                // gll16 per thread per stage
    constexpr int ABPB = AF32 ? 16384 : 8192;      // A bytes per buffer
    __shared__ __align__(16) char sAraw[DEPTH][ABPB];
    __shared__ __align__(16) char sBraw[DEPTH][8192];

    const int t = threadIdx.x;
    const int ntiles = N >> 7;
    const int nwg = gridDim.x;
    const int d = blockIdx.x;
    const int bid = (d & 7) * (nwg >> 3) + (d >> 3);  // XCD swizzle (nwg%8==0)
    const int mtile = bid / ntiles;
    const int ntile = bid % ntiles;
    const int m0 = mtile << 7, n0 = ntile << 7;

    const int lane = t & 63;
    const int wave = t >> 6;            // 0..3 -> 2m x 2n sub-tiles of 64x64
    const int wr = (wave >> 1) * 64;
    const int wc = (wave & 1) * 64;
    const int l15 = lane & 15;
    const int lk  = (lane >> 4) * 8;    // k-elem offset of this lane's frag

    f32x4 acc[4][4];
    #pragma unroll
    for (int m = 0; m < 4; ++m)
        #pragma unroll
        for (int n = 0; n < 4; ++n)
            acc[m][n] = (f32x4){0.f, 0.f, 0.f, 0.f};

    // ---- staging source addresses (pre-swizzled global per rule 21) ----
    // bf16 tiles: 256 thr x 16B = 64 rows/issue; rows r and r+64 share swizzle.
    const int brow = t >> 2;
    const int bslot = ((t & 3) ^ ((brow >> 1) & 3)) * 16;     // bytes
    const char* bsrc = (const char*)Bw + (size_t)(n0 + brow) * K * 2 + bslot;
    const char* asrcb = AF32 ? nullptr
                             : ((const char*)Ab + (size_t)(m0 + brow) * K * 2 + bslot);
    // fp32 A: 32 rows/issue; rows r+32j share swizzle (32%8==0).
    const int ar = t >> 3;
    const int aslot = ((t & 7) ^ (ar & 7)) * 16;
    const char* asrcf = AF32 ? ((const char*)Af + (size_t)(m0 + ar) * K * 4 + aslot)
                             : nullptr;

    auto STAGE = [&](int buf, int kt) {
        if constexpr (AF32) {
            const size_t kb = (size_t)kt * 4;
            gll16(asrcf + kb,                      &sAraw[buf][t * 16]);
            gll16(asrcf + kb + (size_t)32 * K * 4, &sAraw[buf][4096  + t * 16]);
            gll16(asrcf + kb + (size_t)64 * K * 4, &sAraw[buf][8192  + t * 16]);
            gll16(asrcf + kb + (size_t)96 * K * 4, &sAraw[buf][12288 + t * 16]);
        } else {
            const size_t kb = (size_t)kt * 2;
            gll16(asrcb + kb,                      &sAraw[buf][t * 16]);
            gll16(asrcb + kb + (size_t)64 * K * 2, &sAraw[buf][4096 + t * 16]);
        }
        const size_t kb = (size_t)kt * 2;
        gll16(bsrc + kb,                      &sBraw[buf][t * 16]);
        gll16(bsrc + kb + (size_t)64 * K * 2, &sBraw[buf][4096 + t * 16]);
    };

    // ---- LDS read base offsets (m/n fragment steps are +2048/+1024 imm:
    //      swizzle is invariant under +16 rows) ----
    const int Rb = wc + l15;
    const int boff = Rb * 64 + ((lk * 2) ^ (((Rb >> 1) & 3) << 4));
    const int Ra = wr + l15;
    int aoff0, aoff1 = 0;
    if constexpr (AF32) {
        const int s = (Ra & 7) << 4;
        aoff0 = Ra * 128 + ((lk * 4) ^ s);
        aoff1 = Ra * 128 + ((lk * 4 + 16) ^ s);
    } else {
        aoff0 = Ra * 64 + ((lk * 2) ^ (((Ra >> 1) & 3) << 4));
    }

    auto COMPUTE = [&](int buf) {
        const char* aB = sAraw[buf];
        const char* bB = sBraw[buf];
        bf16x8 afr[4], bfr[4];
        #pragma unroll
        for (int m = 0; m < 4; ++m) {
            if constexpr (AF32) {
                f32x4 h0 = *(const f32x4*)(aB + aoff0 + m * 2048);
                f32x4 h1 = *(const f32x4*)(aB + aoff1 + m * 2048);
                afr[m] = (bf16x8){ (bf16)h0.x, (bf16)h0.y, (bf16)h0.z, (bf16)h0.w,
                                   (bf16)h1.x, (bf16)h1.y, (bf16)h1.z, (bf16)h1.w };
            } else {
                afr[m] = *(const bf16x8*)(aB + aoff0 + m * 1024);
            }
        }
        #pragma unroll
        for (int n = 0; n < 4; ++n)
            bfr[n] = *(const bf16x8*)(bB + boff + n * 1024);
        #pragma unroll
        for (int m = 0; m < 4; ++m)
            #pragma unroll
            for (int n = 0; n < 4; ++n)
                acc[m][n] = __builtin_amdgcn_mfma_f32_16x16x32_bf16(
                                afr[m], bfr[n], acc[m][n], 0, 0, 0);
    };

    // ---- prologue: fill the ring ----
    #pragma unroll
    for (int p = 0; p < DEPTH; ++p) STAGE(p, p * 32);

    // ---- steady state ----
    int buf = 0;
    int kt_stage = DEPTH * 32;
    for (int i = 0; i < NSTEP - (DEPTH - 1); ++i) {
        waitvm<(DEPTH - 1) * L>();      // tile i landed; newer stages in flight
        barrier_raw();
        COMPUTE(buf);
        barrier_raw();                  // all waves done reading buf (WAR safe)
        if (kt_stage < K) { STAGE(buf, kt_stage); kt_stage += 32; }
        buf = (buf + 1 == DEPTH) ? 0 : buf + 1;
    }
    // ---- tail ----
    if constexpr (DEPTH == 3) {
        waitvm<L>(); barrier_raw(); COMPUTE(buf);
        buf = (buf + 1 == DEPTH) ? 0 : buf + 1;
    }
    waitvm<0>(); barrier_raw(); COMPUTE(buf);
    asm volatile("" ::: "memory");

    // epilogue: row = wr + m*16 + 4*(lane>>4) + r, col = wc + n*16 + l15
    const int rbase = m0 + wr + ((lane >> 4) << 2);
    const int cbase = n0 + wc + l15;
    #pragma unroll
    for (int n = 0; n < 4; ++n) {
        const int gc = cbase + n * 16;
        const float bv = bias[gc];
        float dec = 0.f;
        if constexpr (EPI == 2) dec = __expf(-0.1f / tau[gc]);
        #pragma unroll
        for (int m = 0; m < 4; ++m) {
            #pragma unroll
            for (int r = 0; r < 4; ++r) {
                const int gr = rbase + m * 16 + r;
                float v = acc[m][n][r] + bv;
                if constexpr (EPI == 1) {
                    float tv = 1.0f - 2.0f / (1.0f + __expf(2.0f * v));
                    outB[(size_t)gr * N + gc] = (bf16)tv;
                } else if constexpr (EPI == 2) {
                    float a = 1.0f / (1.0f + __expf(-v));
                    float s = states[(size_t)gr * N + gc];
                    outF[(size_t)gr * N + gc] = a + (s - a) * dec;
                } else {
                    outF[(size_t)gr * N + gc] = v;
                }
            }
        }
    }
}

extern "C" void kernel_launch(void* const* d_in, const int* in_sizes, int n_in,
                              void* d_out, int out_size, void* d_ws, size_t ws_size,
                              hipStream_t stream) {
    const float* x        = (const float*)d_in[0];
    const float* w_in     = (const float*)d_in[1];
    const float* b_in     = (const float*)d_in[2];
    const float* sens_w   = (const float*)d_in[3];
    const float* sens_sig = (const float*)d_in[4];
    const float* tau      = (const float*)d_in[5];
    const float* ro_w     = (const float*)d_in[6];
    const float* ro_b     = (const float*)d_in[7];
    const float* states   = (const float*)d_in[8];

    float* out    = (float*)d_out;                       // [B][D_OUT] (final, GEMM3)
    float* new_st = out + (size_t)BATCH * D_OUT;         // [B][UNITS] (final, GEMM2)
    bf16*  proj   = (bf16*)d_out;                        // temp bf16 in half1

    bf16* w_in_bf = (bf16*)d_ws;                         // 512*1024
    bf16* sensT   = w_in_bf + (size_t)UNITS * D_IN;      // 512*512 (transposed)
    bf16* ro_bf   = sensT + (size_t)UNITS * UNITS;       // 512*512

    // fused weight prep (single launch)
    k_prep<<<1024, 256, 0, stream>>>(w_in, sens_w, ro_w, w_in_bf, sensT, ro_bf);

    // GEMM1: proj = tanh(x @ w_in^T + b_in) -> bf16 (half1, temp); fp32 A, 2-deep ring
    k_gemm<1024, 1, true, 2><<<(BATCH / 128) * (UNITS / 128), 256, 0, stream>>>(
        x, nullptr, w_in_bf, b_in, nullptr, nullptr, nullptr, proj, BATCH, UNITS);

    // GEMM2: new_st = sig(proj @ sensT^T + sigma); ODE step -> fp32 (half2, final); 3-deep
    k_gemm<512, 2, false, 3><<<(BATCH / 128) * (UNITS / 128), 256, 0, stream>>>(
        nullptr, proj, sensT, sens_sig, tau, states, new_st, nullptr, BATCH, UNITS);

    // GEMM3: out = new_st @ readout^T + ro_b -> fp32 (half1, final); fp32 A, 2-deep
    k_gemm<512, 3, true, 2><<<(BATCH / 128) * (D_OUT / 128), 256, 0, stream>>>(
        new_st, nullptr, ro_bf, ro_b, nullptr, nullptr, out, nullptr, BATCH, D_OUT);
}